// Round 2
// baseline (11218.646 us; speedup 1.0000x reference)
//
#include <hip/hip_runtime.h>
#include <hip/hip_fp16.h>

// LSTM Autoencoder: B=256, T=128, I=512, H=1024, E=256
// Persistent-kernel design:
//  - enc_persist: 256 blocks = 4 row-groups x 64 col-CUs. Weights (fp16 MFMA
//    B-fragments) pinned in 192 VGPRs/lane (k-split across the 4 waves).
//    A-operands (x, h) live in global memory ALREADY in MFMA A-fragment
//    layout -> per-step loads are coalesced dwordx4 direct to MFMA, no LDS.
//    LDS only for the k-split partial reduction + gate epilogue.
//    c-state in registers across all 128 steps. One flag-sync per step.
//  - dec_persist: same, K=512, per-(b,gate) "fixed" bias in registers.
//  - Residency: >256 VGPR => 1 wave/SIMD => 1 block/CU; grid=256 <= capacity,
//    so all blocks resident; spin-sync cannot deadlock.

#define B_ 256
#define T_ 128
#define I_ 512
#define H_ 1024
#define E_ 256

typedef _Float16 half8 __attribute__((ext_vector_type(8)));
typedef float floatx4 __attribute__((ext_vector_type(4)));

__device__ __forceinline__ float sigmoidf_(float x) {
    return 1.0f / (1.0f + __expf(-x));
}
__device__ __forceinline__ float tanhf_(float x) {
    x = fminf(fmaxf(x, -15.0f), 15.0f);
    float e = __expf(2.0f * x);
    return (e - 1.0f) / (e + 1.0f);
}

// ---------------- x -> MFMA A-fragment layout (once) ----------------
// xf tile (t, rt, kc): 64 lanes x 8 fp16; element(lane,sub) = x[b=rt*16+(lane&15)][t][k=kc*32+(lane>>4)*8+sub]
__global__ void shuffle_x_kernel(const float* __restrict__ x, _Float16* __restrict__ xf) {
    const int gg   = blockIdx.x * 256 + threadIdx.x;   // 2,097,152 total
    const int tile = gg >> 6;
    const int lane = gg & 63;
    const int t  = tile >> 8;
    const int rt = (tile >> 4) & 15;
    const int kc = tile & 15;
    const int b  = rt * 16 + (lane & 15);
    const int j0 = kc * 32 + ((lane >> 4) << 3);
    const float* src = x + ((size_t)b * T_ + t) * I_ + j0;
    float4 f0 = *(const float4*)src;
    float4 f1 = *(const float4*)(src + 4);
    half8 h = { (_Float16)f0.x, (_Float16)f0.y, (_Float16)f0.z, (_Float16)f0.w,
                (_Float16)f1.x, (_Float16)f1.y, (_Float16)f1.z, (_Float16)f1.w };
    *(half8*)(xf + (size_t)tile * 512 + lane * 8) = h;
}

// ---------------- small fp32 GEMM (unchanged, correct) ----------------
__global__ __launch_bounds__(256) void small_gemm_kernel(
    const float* __restrict__ A, int lda,
    const float* __restrict__ W, int ldw,
    const float* __restrict__ b1, const float* __restrict__ b2,
    float* __restrict__ out, int N, int K, int relu)
{
    __shared__ float sA2[32][33];
    __shared__ float sW2[32][33];
    int tid = threadIdx.x;
    int tx = tid & 15, ty = tid >> 4;
    int m0 = blockIdx.y * 32, n0 = blockIdx.x * 32;
    float acc[2][2] = {};
    for (int k0 = 0; k0 < K; k0 += 32) {
        __syncthreads();
#pragma unroll
        for (int i = 0; i < 4; ++i) {
            int e = tid + i * 256;
            int r = e >> 5, c = e & 31;
            sA2[r][c] = A[(size_t)(m0 + r) * lda + k0 + c];
            sW2[r][c] = W[(size_t)(n0 + r) * ldw + k0 + c];
        }
        __syncthreads();
#pragma unroll
        for (int k = 0; k < 32; ++k) {
            float a0 = sA2[ty * 2][k], a1 = sA2[ty * 2 + 1][k];
            float w0 = sW2[tx * 2][k], w1 = sW2[tx * 2 + 1][k];
            acc[0][0] += a0 * w0; acc[0][1] += a0 * w1;
            acc[1][0] += a1 * w0; acc[1][1] += a1 * w1;
        }
    }
#pragma unroll
    for (int i = 0; i < 2; ++i)
#pragma unroll
        for (int j = 0; j < 2; ++j) {
            int m = m0 + ty * 2 + i, n = n0 + tx * 2 + j;
            float v = acc[i][j] + b1[n] + (b2 ? b2[n] : 0.0f);
            if (relu) v = fmaxf(v, 0.0f);
            out[(size_t)m * N + n] = v;
        }
}

// ---------------- persistent encoder ----------------
// hbuf: [2][rt 16][kc 32][lane 64][8] fp16 (A-fragment layout, K-offset 512.. = h)
__global__ __launch_bounds__(256, 1) void enc_persist(
    const _Float16* __restrict__ xf,
    const float* __restrict__ Wih,
    const float* __restrict__ Whh,
    const float* __restrict__ bih,
    const float* __restrict__ bhh,
    _Float16* __restrict__ hbuf,
    float* __restrict__ c_out,
    int* __restrict__ flags)
{
    const int tid  = threadIdx.x;
    const int wave = tid >> 6;
    const int lane = tid & 63;
    const int q    = lane >> 4;
    const int n15  = lane & 15;
    const int blk  = blockIdx.x;
    const int rg   = (blk & 7) >> 1;                 // row-group 0..3 (XCD-pair local)
    const int cc   = ((blk >> 3) << 1) | (blk & 1);  // col-CU 0..63

    // ---- weights -> registers: wave w holds k in [384w, 384w+384), 64 gate-cols ----
    half8 bw[4][12];
#pragma unroll
    for (int g = 0; g < 4; ++g) {
        const int jc = g * H_ + cc * 16 + n15;
#pragma unroll
        for (int kc = 0; kc < 12; ++kc) {
            const int k = wave * 384 + kc * 32 + q * 8;
            const float* src = (k < I_) ? (Wih + (size_t)jc * I_ + k)
                                        : (Whh + (size_t)jc * H_ + (k - I_));
            float4 f0 = *(const float4*)src;
            float4 f1 = *(const float4*)(src + 4);
            bw[g][kc] = half8{(_Float16)f0.x, (_Float16)f0.y, (_Float16)f0.z, (_Float16)f0.w,
                              (_Float16)f1.x, (_Float16)f1.y, (_Float16)f1.z, (_Float16)f1.w};
        }
    }

    const int hcT = tid & 15;   // owned h-col (within CU's 16)
    const int rT  = tid >> 4;   // owned row base 0..15
    float breg[4];
#pragma unroll
    for (int g = 0; g < 4; ++g) {
        const int j = g * H_ + cc * 16 + hcT;
        breg[g] = bih[j] + bhh[j];
    }
    float creg[4] = {0.f, 0.f, 0.f, 0.f};   // rows rT, 16+rT, 32+rT, 48+rT

    __shared__ float preT[4][64][33];   // [k-wave][col][row(32, padded)]

    for (int s = 0; s < T_; ++s) {
        const _Float16* __restrict__ hcur = hbuf + (size_t)(s & 1) * 262144;
        _Float16* __restrict__ hnxt = hbuf + (size_t)((s + 1) & 1) * 262144;
        const size_t laneoff = (size_t)lane * 8;

        floatx4 acc[4][4];
#pragma unroll
        for (int m = 0; m < 4; ++m)
#pragma unroll
            for (int n = 0; n < 4; ++n) acc[m][n] = floatx4{0.f, 0.f, 0.f, 0.f};

        // software-pipelined direct global->VGPR A-fragments (depth 4)
        half8 Abuf[4][4];
#pragma unroll
        for (int kcl = 0; kcl < 4; ++kcl) {
            const int kg = wave * 12 + kcl;
#pragma unroll
            for (int m = 0; m < 4; ++m) {
                const int rt = rg * 4 + m;
                const _Float16* ap = (kg < 16)
                    ? (xf + (((size_t)s * 16 + rt) * 16 + kg) * 512 + laneoff)
                    : (hcur + ((size_t)rt * 32 + (kg - 16)) * 512 + laneoff);
                Abuf[kcl][m] = *(const half8*)ap;
            }
        }
#pragma unroll
        for (int kcl = 0; kcl < 12; ++kcl) {
            const int sl = kcl & 3;
#pragma unroll
            for (int n = 0; n < 4; ++n)
#pragma unroll
                for (int m = 0; m < 4; ++m)
                    acc[m][n] = __builtin_amdgcn_mfma_f32_16x16x32_f16(
                        Abuf[sl][m], bw[n][kcl], acc[m][n], 0, 0, 0);
            if (kcl < 8) {
                const int kg = wave * 12 + kcl + 4;
#pragma unroll
                for (int m = 0; m < 4; ++m) {
                    const int rt = rg * 4 + m;
                    const _Float16* ap = (kg < 16)
                        ? (xf + (((size_t)s * 16 + rt) * 16 + kg) * 512 + laneoff)
                        : (hcur + ((size_t)rt * 32 + (kg - 16)) * 512 + laneoff);
                    Abuf[sl][m] = *(const half8*)ap;
                }
            }
        }

        // ---- epilogue phase A: rows 0..31 (m-tiles 0,1) ----
        // (preT free: previous step's readers all passed the flag barrier)
#pragma unroll
        for (int m = 0; m < 2; ++m)
#pragma unroll
            for (int n = 0; n < 4; ++n)
                *(floatx4*)&preT[wave][n * 16 + n15][m * 16 + q * 4] = acc[m][n];
        __syncthreads();
#pragma unroll
        for (int p = 0; p < 2; ++p) {
            const int r = p * 16 + rT;
            float pg[4];
#pragma unroll
            for (int g = 0; g < 4; ++g)
                pg[g] = preT[0][g * 16 + hcT][r] + preT[1][g * 16 + hcT][r]
                      + preT[2][g * 16 + hcT][r] + preT[3][g * 16 + hcT][r] + breg[g];
            const float ig = sigmoidf_(pg[0]);
            const float fg = sigmoidf_(pg[1]);
            const float gg = tanhf_(pg[2]);
            const float og = sigmoidf_(pg[3]);
            const float c  = fg * creg[p] + ig * gg;
            creg[p] = c;
            const float h = og * tanhf_(c);
            const int hg  = cc * 16 + hcT;
            const int kch = hg >> 5, j = hg & 31;
            const int lt  = (r & 15) | ((j >> 3) << 4);
            hnxt[((size_t)(rg * 4 + (r >> 4)) * 32 + kch) * 512 + lt * 8 + (j & 7)] = (_Float16)h;
        }
        __syncthreads();
        // ---- epilogue phase B: rows 32..63 (m-tiles 2,3) ----
#pragma unroll
        for (int m = 0; m < 2; ++m)
#pragma unroll
            for (int n = 0; n < 4; ++n)
                *(floatx4*)&preT[wave][n * 16 + n15][m * 16 + q * 4] = acc[m + 2][n];
        __syncthreads();
#pragma unroll
        for (int p = 0; p < 2; ++p) {
            const int rr = p * 16 + rT;
            const int r  = 32 + rr;
            float pg[4];
#pragma unroll
            for (int g = 0; g < 4; ++g)
                pg[g] = preT[0][g * 16 + hcT][rr] + preT[1][g * 16 + hcT][rr]
                      + preT[2][g * 16 + hcT][rr] + preT[3][g * 16 + hcT][rr] + breg[g];
            const float ig = sigmoidf_(pg[0]);
            const float fg = sigmoidf_(pg[1]);
            const float gg = tanhf_(pg[2]);
            const float og = sigmoidf_(pg[3]);
            const float c  = fg * creg[2 + p] + ig * gg;
            creg[2 + p] = c;
            const float h = og * tanhf_(c);
            const int hg  = cc * 16 + hcT;
            const int kch = hg >> 5, j = hg & 31;
            const int lt  = (r & 15) | ((j >> 3) << 4);
            hnxt[((size_t)(rg * 4 + (r >> 4)) * 32 + kch) * 512 + lt * 8 + (j & 7)] = (_Float16)h;
        }
        __syncthreads();          // all h-stores issued before release
        __threadfence();          // agent release: L2 writeback (cross-XCD)
        if (tid == 0)
            __hip_atomic_store(&flags[blk], s + 1, __ATOMIC_RELAXED, __HIP_MEMORY_SCOPE_AGENT);
        if (tid < 64) {
            const int wb = ((tid >> 1) << 3) | (rg << 1) | (tid & 1);  // 64 blocks of my row-group
            while (__hip_atomic_load(&flags[wb], __ATOMIC_RELAXED, __HIP_MEMORY_SCOPE_AGENT) < s + 1)
                __builtin_amdgcn_s_sleep(2);
        }
        __syncthreads();
        __threadfence();          // agent acquire: invalidate stale lines
    }

    // final cell state -> global (embd input)
#pragma unroll
    for (int ci = 0; ci < 4; ++ci) {
        const int r = ci * 16 + rT;
        c_out[(size_t)(rg * 64 + r) * H_ + cc * 16 + hcT] = creg[ci];
    }
}

// ---------------- persistent decoder ----------------
// hbuf: [2][rt 16][kc 16][lane 64][8] fp16
__global__ __launch_bounds__(256, 1) void dec_persist(
    const float* __restrict__ dWih,
    const float* __restrict__ dWhh,
    const float* __restrict__ fixedb,
    _Float16* __restrict__ hbuf,
    float* __restrict__ out,
    int* __restrict__ flags)
{
    const int tid  = threadIdx.x;
    const int wave = tid >> 6;
    const int lane = tid & 63;
    const int q    = lane >> 4;
    const int n15  = lane & 15;
    const int blk  = blockIdx.x;
    const int rg   = (blk & 7) >> 1;
    const int cc   = ((blk >> 3) << 1) | (blk & 1);  // 0..63, 8 h-cols each

    // W_rec[j][k] = dWih[j][1024+k] + dWhh[j][k]; wave w: k in [128w, 128w+128)
    // n-tile n covers gates 2n,2n+1: col15 -> g=2n+(col15>>3), hc=col15&7
    half8 bw[2][4];
#pragma unroll
    for (int n = 0; n < 2; ++n) {
        const int jc = (n * 2 + (n15 >> 3)) * I_ + cc * 8 + (n15 & 7);
#pragma unroll
        for (int kc = 0; kc < 4; ++kc) {
            const int k = wave * 128 + kc * 32 + q * 8;
            const float* s0 = dWih + (size_t)jc * (H_ + I_) + H_ + k;
            const float* s1 = dWhh + (size_t)jc * I_ + k;
            float4 a0 = *(const float4*)s0, a1 = *(const float4*)(s0 + 4);
            float4 b0 = *(const float4*)s1, b1 = *(const float4*)(s1 + 4);
            bw[n][kc] = half8{(_Float16)(a0.x + b0.x), (_Float16)(a0.y + b0.y),
                              (_Float16)(a0.z + b0.z), (_Float16)(a0.w + b0.w),
                              (_Float16)(a1.x + b1.x), (_Float16)(a1.y + b1.y),
                              (_Float16)(a1.z + b1.z), (_Float16)(a1.w + b1.w)};
        }
    }

    const int hcT = tid & 7;    // owned h-col
    const int rT  = tid >> 3;   // 0..31
    float fxreg[2][4];
    float creg[2] = {0.f, 0.f};
#pragma unroll
    for (int p = 0; p < 2; ++p) {
        const int b = rg * 64 + p * 32 + rT;
#pragma unroll
        for (int g = 0; g < 4; ++g)
            fxreg[p][g] = fixedb[(size_t)b * (4 * I_) + g * I_ + cc * 8 + hcT];
    }

    __shared__ float preT[4][32][65];   // [k-wave][col 32][row 64 padded]

    for (int s = 0; s < T_; ++s) {
        const _Float16* __restrict__ hcur = hbuf + (size_t)(s & 1) * 131072;
        _Float16* __restrict__ hnxt = hbuf + (size_t)((s + 1) & 1) * 131072;
        const size_t laneoff = (size_t)lane * 8;

        floatx4 acc[4][2];
#pragma unroll
        for (int m = 0; m < 4; ++m)
#pragma unroll
            for (int n = 0; n < 2; ++n) acc[m][n] = floatx4{0.f, 0.f, 0.f, 0.f};

        half8 Abuf[4][4];
#pragma unroll
        for (int kcl = 0; kcl < 4; ++kcl) {
            const int kg = wave * 4 + kcl;
#pragma unroll
            for (int m = 0; m < 4; ++m)
                Abuf[kcl][m] = *(const half8*)(hcur + ((size_t)(rg * 4 + m) * 16 + kg) * 512 + laneoff);
        }
#pragma unroll
        for (int kcl = 0; kcl < 4; ++kcl)
#pragma unroll
            for (int n = 0; n < 2; ++n)
#pragma unroll
                for (int m = 0; m < 4; ++m)
                    acc[m][n] = __builtin_amdgcn_mfma_f32_16x16x32_f16(
                        Abuf[kcl][m], bw[n][kcl], acc[m][n], 0, 0, 0);

        // single-phase epilogue (64 rows x 32 cols fits padded in 33 KB)
#pragma unroll
        for (int m = 0; m < 4; ++m)
#pragma unroll
            for (int n = 0; n < 2; ++n)
                *(floatx4*)&preT[wave][n * 16 + n15][m * 16 + q * 4] = acc[m][n];
        __syncthreads();
#pragma unroll
        for (int p = 0; p < 2; ++p) {
            const int r = p * 32 + rT;
            float pg[4];
#pragma unroll
            for (int g = 0; g < 4; ++g) {
                const int col = (g >> 1) * 16 + (g & 1) * 8 + hcT;
                pg[g] = preT[0][col][r] + preT[1][col][r]
                      + preT[2][col][r] + preT[3][col][r] + fxreg[p][g];
            }
            const float ig = sigmoidf_(pg[0]);
            const float fg = sigmoidf_(pg[1]);
            const float gg = tanhf_(pg[2]);
            const float og = sigmoidf_(pg[3]);
            const float c  = fg * creg[p] + ig * gg;
            creg[p] = c;
            const float h = og * tanhf_(c);
            const int b = rg * 64 + r;
            out[((size_t)b * T_ + (T_ - 1 - s)) * I_ + cc * 8 + hcT] = h;
            const int hg  = cc * 8 + hcT;
            const int kch = hg >> 5, j = hg & 31;
            const int lt  = (r & 15) | ((j >> 3) << 4);
            hnxt[((size_t)(rg * 4 + (r >> 4)) * 16 + kch) * 512 + lt * 8 + (j & 7)] = (_Float16)h;
        }
        __syncthreads();
        __threadfence();
        if (tid == 0)
            __hip_atomic_store(&flags[blk], s + 1, __ATOMIC_RELAXED, __HIP_MEMORY_SCOPE_AGENT);
        if (tid < 64) {
            const int wb = ((tid >> 1) << 3) | (rg << 1) | (tid & 1);
            while (__hip_atomic_load(&flags[wb], __ATOMIC_RELAXED, __HIP_MEMORY_SCOPE_AGENT) < s + 1)
                __builtin_amdgcn_s_sleep(2);
        }
        __syncthreads();
        __threadfence();
    }
}

// ---------------- launch ----------------
extern "C" void kernel_launch(void* const* d_in, const int* in_sizes, int n_in,
                              void* d_out_v, int out_size, void* d_ws, size_t ws_size,
                              hipStream_t stream) {
    (void)in_sizes; (void)n_in; (void)out_size; (void)ws_size;
    const float* x    = (const float*)d_in[0];
    const float* eWih = (const float*)d_in[1];
    const float* eWhh = (const float*)d_in[2];
    const float* ebih = (const float*)d_in[3];
    const float* ebhh = (const float*)d_in[4];
    const float* efcW = (const float*)d_in[5];
    const float* efcb = (const float*)d_in[6];
    const float* dfcW = (const float*)d_in[7];
    const float* dfcb = (const float*)d_in[8];
    const float* dWih = (const float*)d_in[9];
    const float* dWhh = (const float*)d_in[10];
    const float* dbih = (const float*)d_in[11];
    const float* dbhh = (const float*)d_in[12];
    float* d_out = (float*)d_out_v;

    char* ws = (char*)d_ws;
    size_t off = 0;
    auto carve = [&](size_t bytes) {
        char* p = ws + off;
        off += (bytes + 255) & ~(size_t)255;
        return p;
    };
    _Float16* xf     = (_Float16*)carve((size_t)B_ * T_ * I_ * 2);   // 33.6 MB
    _Float16* hbufE  = (_Float16*)carve((size_t)2 * 262144 * 2);     // 1 MB
    _Float16* hbufD  = (_Float16*)carve((size_t)2 * 131072 * 2);     // 0.5 MB
    float*    c_e    = (float*)carve((size_t)B_ * H_ * 4);           // 1 MB
    float*    fixedb = (float*)carve((size_t)B_ * 4 * I_ * 4);       // 2 MB
    float*    dec1   = (float*)carve((size_t)B_ * H_ * 4);           // 1 MB
    int*      flagsE = (int*)carve(256 * 4);
    int*      flagsD = (int*)carve(256 * 4);

    hipMemsetAsync(flagsE, 0, 256 * 4, stream);
    hipMemsetAsync(flagsD, 0, 256 * 4, stream);
    hipMemsetAsync(hbufE, 0, (size_t)262144 * 2, stream);   // h0 = 0 (buf 0)
    hipMemsetAsync(hbufD, 0, (size_t)131072 * 2, stream);   // hd0 = 0 (buf 0)

    shuffle_x_kernel<<<dim3(8192), 256, 0, stream>>>(x, xf);

    enc_persist<<<dim3(256), 256, 0, stream>>>(xf, eWih, eWhh, ebih, ebhh,
                                               hbufE, c_e, flagsE);

    float* embd = d_out + (size_t)B_ * T_ * I_;
    // embd = relu(c_final @ encfc_W.T + encfc_b)   [256 x 256], K=1024
    small_gemm_kernel<<<dim3(E_ / 32, B_ / 32), 256, 0, stream>>>(
        c_e, H_, efcW, H_, efcb, nullptr, embd, E_, H_, 1);
    // dec_first = relu(embd @ decfc_W.T + decfc_b) [256 x 1024], K=256
    small_gemm_kernel<<<dim3(H_ / 32, B_ / 32), 256, 0, stream>>>(
        embd, E_, dfcW, E_, dfcb, nullptr, dec1, H_, E_, 1);
    // fixed = dec_first @ dec_Wih[:, :H].T + (dec_bih + dec_bhh) [256 x 2048], K=1024
    small_gemm_kernel<<<dim3(4 * I_ / 32, B_ / 32), 256, 0, stream>>>(
        dec1, H_, dWih, H_ + I_, dbih, dbhh, fixedb, 4 * I_, H_, 0);

    dec_persist<<<dim3(256), 256, 0, stream>>>(dWih, dWhh, fixedb,
                                               hbufD, d_out, flagsD);
}

// Round 3
// 1843.177 us; speedup vs baseline: 6.0866x; 6.0866x over previous
//
#include <hip/hip_runtime.h>
#include <hip/hip_fp16.h>

// LSTM Autoencoder: B=256, T=128, I=512, H=1024, E=256
// Persistent kernels, weights pinned in VGPRs, cross-block handoff via
// word-granular coherent (sc0+sc1) atomics at AGENT scope -- NO threadfence
// (round-2 post-mortem: buffer_wbl2/buffer_inv cache walks cost ~45 us/step).
// Protocol per step: poll flags(>=s) -> sc1 h-loads -> MFMA -> epilogue ->
// sc1 h-stores -> vmcnt(0)+barrier -> flag=s+1.  x-fragment loads + x-MFMAs
// run BEFORE the poll (independent of h) to hide sync latency.

#define B_ 256
#define T_ 128
#define I_ 512
#define H_ 1024
#define E_ 256

typedef _Float16 half8 __attribute__((ext_vector_type(8)));
typedef float floatx4 __attribute__((ext_vector_type(4)));

__device__ __forceinline__ float sigmoidf_(float x) { return 1.0f / (1.0f + __expf(-x)); }
__device__ __forceinline__ float tanhf_(float x) {
    x = fminf(fmaxf(x, -15.0f), 15.0f);
    float e = __expf(2.0f * x);
    return (e - 1.0f) / (e + 1.0f);
}

// coherent 16B load as 2x u64 relaxed-agent atomics (emit global_load_dwordx2 sc0 sc1)
__device__ __forceinline__ half8 ldg_h8_sc1(const _Float16* p) {
    union { unsigned long long u[2]; half8 h; } v;
    const unsigned long long* q = (const unsigned long long*)p;
    v.u[0] = __hip_atomic_load(q,     __ATOMIC_RELAXED, __HIP_MEMORY_SCOPE_AGENT);
    v.u[1] = __hip_atomic_load(q + 1, __ATOMIC_RELAXED, __HIP_MEMORY_SCOPE_AGENT);
    return v.h;
}
// coherent store of 2 adjacent fp16
__device__ __forceinline__ void stg_h2_sc1(_Float16* p, float a, float b) {
    union { _Float16 h[2]; unsigned int u; } v;
    v.h[0] = (_Float16)a; v.h[1] = (_Float16)b;
    __hip_atomic_store((unsigned int*)p, v.u, __ATOMIC_RELAXED, __HIP_MEMORY_SCOPE_AGENT);
}
__device__ __forceinline__ void wait_vm0() {
    asm volatile("s_waitcnt vmcnt(0)" ::: "memory");
}
// each lane watches one of the row-group's 64 flags
__device__ __forceinline__ void poll_rg(int* flags, int rgbase, int lane, int target) {
    while (__hip_atomic_load(&flags[rgbase + lane], __ATOMIC_RELAXED, __HIP_MEMORY_SCOPE_AGENT) < target)
        __builtin_amdgcn_s_sleep(1);
    asm volatile("" ::: "memory");
}

// ---------------- x -> MFMA A-fragment layout (once) ----------------
__global__ void shuffle_x_kernel(const float* __restrict__ x, _Float16* __restrict__ xf) {
    const int gg   = blockIdx.x * 256 + threadIdx.x;
    const int tile = gg >> 6;
    const int lane = gg & 63;
    const int t  = tile >> 8;
    const int rt = (tile >> 4) & 15;
    const int kc = tile & 15;
    const int b  = rt * 16 + (lane & 15);
    const int j0 = kc * 32 + ((lane >> 4) << 3);
    const float* src = x + ((size_t)b * T_ + t) * I_ + j0;
    float4 f0 = *(const float4*)src;
    float4 f1 = *(const float4*)(src + 4);
    half8 h = { (_Float16)f0.x, (_Float16)f0.y, (_Float16)f0.z, (_Float16)f0.w,
                (_Float16)f1.x, (_Float16)f1.y, (_Float16)f1.z, (_Float16)f1.w };
    *(half8*)(xf + (size_t)tile * 512 + lane * 8) = h;
}

// ---------------- small fp32 GEMM ----------------
__global__ __launch_bounds__(256) void small_gemm_kernel(
    const float* __restrict__ A, int lda,
    const float* __restrict__ W, int ldw,
    const float* __restrict__ b1, const float* __restrict__ b2,
    float* __restrict__ out, int N, int K, int relu)
{
    __shared__ float sA2[32][33];
    __shared__ float sW2[32][33];
    int tid = threadIdx.x;
    int tx = tid & 15, ty = tid >> 4;
    int m0 = blockIdx.y * 32, n0 = blockIdx.x * 32;
    float acc[2][2] = {};
    for (int k0 = 0; k0 < K; k0 += 32) {
        __syncthreads();
#pragma unroll
        for (int i = 0; i < 4; ++i) {
            int e = tid + i * 256;
            int r = e >> 5, c = e & 31;
            sA2[r][c] = A[(size_t)(m0 + r) * lda + k0 + c];
            sW2[r][c] = W[(size_t)(n0 + r) * ldw + k0 + c];
        }
        __syncthreads();
#pragma unroll
        for (int k = 0; k < 32; ++k) {
            float a0 = sA2[ty * 2][k], a1 = sA2[ty * 2 + 1][k];
            float w0 = sW2[tx * 2][k], w1 = sW2[tx * 2 + 1][k];
            acc[0][0] += a0 * w0; acc[0][1] += a0 * w1;
            acc[1][0] += a1 * w0; acc[1][1] += a1 * w1;
        }
    }
#pragma unroll
    for (int i = 0; i < 2; ++i)
#pragma unroll
        for (int j = 0; j < 2; ++j) {
            int m = m0 + ty * 2 + i, n = n0 + tx * 2 + j;
            float v = acc[i][j] + b1[n] + (b2 ? b2[n] : 0.0f);
            if (relu) v = fmaxf(v, 0.0f);
            out[(size_t)m * N + n] = v;
        }
}

// ---------------- persistent encoder ----------------
// grid 256 = 4 row-groups (64 batch rows) x 64 col-CUs (16 h-cols -> 64 gate-cols)
// wave w holds k-chunks kg = 4*kc + w (kc=0..11); kg<16 => x (plain loads), else h (sc1)
__global__ __launch_bounds__(256, 1) void enc_persist(
    const _Float16* __restrict__ xf,
    const float* __restrict__ Wih, const float* __restrict__ Whh,
    const float* __restrict__ bih, const float* __restrict__ bhh,
    _Float16* __restrict__ hbuf, float* __restrict__ c_out, int* __restrict__ flags)
{
    const int tid  = threadIdx.x;
    const int wave = tid >> 6, lane = tid & 63;
    const int q = lane >> 4, n15 = lane & 15;
    const int blk = blockIdx.x;
    const int rg = blk >> 6, cc = blk & 63;

    // weights -> VGPRs (192 regs/lane)
    half8 bw[4][12];
#pragma unroll
    for (int g = 0; g < 4; ++g) {
        const int jc = g * H_ + cc * 16 + n15;
#pragma unroll
        for (int kc = 0; kc < 12; ++kc) {
            const int k = (4 * kc + wave) * 32 + q * 8;
            const float* src = (k < I_) ? (Wih + (size_t)jc * I_ + k)
                                        : (Whh + (size_t)jc * H_ + (k - I_));
            float4 f0 = *(const float4*)src;
            float4 f1 = *(const float4*)(src + 4);
            bw[g][kc] = half8{(_Float16)f0.x, (_Float16)f0.y, (_Float16)f0.z, (_Float16)f0.w,
                              (_Float16)f1.x, (_Float16)f1.y, (_Float16)f1.z, (_Float16)f1.w};
        }
    }

    const int hcp = tid & 7;    // owned col-pair (2*hcp, 2*hcp+1)
    const int rT  = tid >> 3;   // owned row (phase A: rT, phase B: 32+rT)
    float breg[4][2];
#pragma unroll
    for (int g = 0; g < 4; ++g)
#pragma unroll
        for (int e = 0; e < 2; ++e) {
            const int j = g * H_ + cc * 16 + 2 * hcp + e;
            breg[g][e] = bih[j] + bhh[j];
        }
    float creg[2][2] = {{0.f, 0.f}, {0.f, 0.f}};

    // [wave][col 64][row 32 pad 35]: b32 access pattern <=2-way banks (free)
    __shared__ float preT[4][64][35];
    const size_t laneoff = (size_t)lane * 8;

    for (int s = 0; s < T_; ++s) {
        const _Float16* __restrict__ hcur = hbuf + (size_t)(s & 1) * 262144;
        _Float16* __restrict__ hnxt = hbuf + (size_t)((s + 1) & 1) * 262144;

        floatx4 acc[4][4];
#pragma unroll
        for (int m = 0; m < 4; ++m)
#pragma unroll
            for (int n = 0; n < 4; ++n) acc[m][n] = floatx4{0.f, 0.f, 0.f, 0.f};

        // ---- x phase (independent of h): load + 64 MFMAs, hides poll latency
        half8 X[4][4];
#pragma unroll
        for (int kc = 0; kc < 4; ++kc)
#pragma unroll
            for (int m = 0; m < 4; ++m)
                X[kc][m] = *(const half8*)(xf + (((size_t)s * 16 + rg * 4 + m) * 16
                                                + (4 * kc + wave)) * 512 + laneoff);
#pragma unroll
        for (int kc = 0; kc < 4; ++kc)
#pragma unroll
            for (int n = 0; n < 4; ++n)
#pragma unroll
                for (int m = 0; m < 4; ++m)
                    acc[m][n] = __builtin_amdgcn_mfma_f32_16x16x32_f16(
                        X[kc][m], bw[n][kc], acc[m][n], 0, 0, 0);

        // ---- wait for h_s (all row-group blocks finished step s-1)
        poll_rg(flags, rg * 64, lane, s);

        // ---- h phase: depth-4 pipelined sc1 loads + 128 MFMAs
        half8 Hb[4][4];
#pragma unroll
        for (int kc = 4; kc < 8; ++kc)
#pragma unroll
            for (int m = 0; m < 4; ++m)
                Hb[kc - 4][m] = ldg_h8_sc1(hcur + ((size_t)(rg * 4 + m) * 32
                                                   + (4 * kc + wave - 16)) * 512 + laneoff);
#pragma unroll
        for (int kc = 4; kc < 12; ++kc) {
            const int sl = kc & 3;
#pragma unroll
            for (int n = 0; n < 4; ++n)
#pragma unroll
                for (int m = 0; m < 4; ++m)
                    acc[m][n] = __builtin_amdgcn_mfma_f32_16x16x32_f16(
                        Hb[sl][m], bw[n][kc], acc[m][n], 0, 0, 0);
            if (kc < 8) {
#pragma unroll
                for (int m = 0; m < 4; ++m)
                    Hb[sl][m] = ldg_h8_sc1(hcur + ((size_t)(rg * 4 + m) * 32
                                                   + (4 * (kc + 4) + wave - 16)) * 512 + laneoff);
            }
        }

        // ---- epilogue: 2 phases (rows 0..31, 32..63)
#pragma unroll
        for (int p = 0; p < 2; ++p) {
            if (p) __syncthreads();   // phase-A reads done before phase-B writes
#pragma unroll
            for (int m = 0; m < 2; ++m)
#pragma unroll
                for (int n = 0; n < 4; ++n)
#pragma unroll
                    for (int r = 0; r < 4; ++r)
                        preT[wave][n * 16 + n15][m * 16 + q * 4 + r] = acc[p * 2 + m][n][r];
            __syncthreads();
            float pg[4][2];
#pragma unroll
            for (int g = 0; g < 4; ++g)
#pragma unroll
                for (int e = 0; e < 2; ++e) {
                    const int col = g * 16 + 2 * hcp + e;
                    pg[g][e] = preT[0][col][rT] + preT[1][col][rT]
                             + preT[2][col][rT] + preT[3][col][rT] + breg[g][e];
                }
            float hv[2];
#pragma unroll
            for (int e = 0; e < 2; ++e) {
                const float ig = sigmoidf_(pg[0][e]);
                const float fg = sigmoidf_(pg[1][e]);
                const float gg = tanhf_(pg[2][e]);
                const float og = sigmoidf_(pg[3][e]);
                const float c  = fg * creg[p][e] + ig * gg;
                creg[p][e] = c;
                hv[e] = og * tanhf_(c);
            }
            const int row = p * 32 + rT;
            const int j   = cc * 16 + 2 * hcp;
            const int kch = j >> 5, j5 = j & 31;
            const int lt  = (row & 15) | ((j5 >> 3) << 4);
            stg_h2_sc1(hnxt + ((size_t)(rg * 4 + (row >> 4)) * 32 + kch) * 512
                            + lt * 8 + (j5 & 7), hv[0], hv[1]);
        }

        wait_vm0();          // all this wave's sc1 h-stores complete (visible at LLC)
        __syncthreads();     // all waves' stores complete
        if (tid == 0)
            __hip_atomic_store(&flags[blk], s + 1, __ATOMIC_RELAXED, __HIP_MEMORY_SCOPE_AGENT);
    }

    // final cell state (plain stores; visible via kernel-end release)
#pragma unroll
    for (int p = 0; p < 2; ++p)
        *(float2*)(c_out + (size_t)(rg * 64 + p * 32 + rT) * H_ + cc * 16 + 2 * hcp)
            = float2{creg[p][0], creg[p][1]};
}

// ---------------- persistent decoder ----------------
__global__ __launch_bounds__(256, 1) void dec_persist(
    const float* __restrict__ dWih, const float* __restrict__ dWhh,
    const float* __restrict__ fixedb,
    _Float16* __restrict__ hbuf, float* __restrict__ out, int* __restrict__ flags)
{
    const int tid  = threadIdx.x;
    const int wave = tid >> 6, lane = tid & 63;
    const int q = lane >> 4, n15 = lane & 15;
    const int blk = blockIdx.x;
    const int rg = blk >> 6, cc = blk & 63;

    // W_rec = dWih[:,H:] + dWhh; wave w: k in [128w,128w+128)
    // n-tile n covers gates 2n,2n+1: col15 -> g=2n+(col15>>3), hc=col15&7
    half8 bw[2][4];
#pragma unroll
    for (int n = 0; n < 2; ++n) {
        const int jc = (n * 2 + (n15 >> 3)) * I_ + cc * 8 + (n15 & 7);
#pragma unroll
        for (int kc = 0; kc < 4; ++kc) {
            const int k = wave * 128 + kc * 32 + q * 8;
            const float* s0 = dWih + (size_t)jc * (H_ + I_) + H_ + k;
            const float* s1 = dWhh + (size_t)jc * I_ + k;
            float4 a0 = *(const float4*)s0, a1 = *(const float4*)(s0 + 4);
            float4 b0 = *(const float4*)s1, b1 = *(const float4*)(s1 + 4);
            bw[n][kc] = half8{(_Float16)(a0.x + b0.x), (_Float16)(a0.y + b0.y),
                              (_Float16)(a0.z + b0.z), (_Float16)(a0.w + b0.w),
                              (_Float16)(a1.x + b1.x), (_Float16)(a1.y + b1.y),
                              (_Float16)(a1.z + b1.z), (_Float16)(a1.w + b1.w)};
        }
    }

    const int hcp = tid & 3;    // col-pair
    const int rT  = tid >> 2;   // row 0..63
    const int brow = rg * 64 + rT;
    float fx[4][2];
#pragma unroll
    for (int g = 0; g < 4; ++g)
#pragma unroll
        for (int e = 0; e < 2; ++e)
            fx[g][e] = fixedb[(size_t)brow * (4 * I_) + g * I_ + cc * 8 + 2 * hcp + e];
    float creg2[2] = {0.f, 0.f};

    __shared__ float preT[4][32][67];
    const size_t laneoff = (size_t)lane * 8;

    for (int s = 0; s < T_; ++s) {
        const _Float16* __restrict__ hcur = hbuf + (size_t)(s & 1) * 131072;
        _Float16* __restrict__ hnxt = hbuf + (size_t)((s + 1) & 1) * 131072;

        poll_rg(flags, rg * 64, lane, s);

        half8 Hb[4][4];
#pragma unroll
        for (int kc = 0; kc < 4; ++kc)
#pragma unroll
            for (int m = 0; m < 4; ++m)
                Hb[kc][m] = ldg_h8_sc1(hcur + ((size_t)(rg * 4 + m) * 16
                                               + (wave * 4 + kc)) * 512 + laneoff);
        floatx4 acc[4][2];
#pragma unroll
        for (int m = 0; m < 4; ++m)
#pragma unroll
            for (int n = 0; n < 2; ++n) acc[m][n] = floatx4{0.f, 0.f, 0.f, 0.f};
#pragma unroll
        for (int kc = 0; kc < 4; ++kc)
#pragma unroll
            for (int n = 0; n < 2; ++n)
#pragma unroll
                for (int m = 0; m < 4; ++m)
                    acc[m][n] = __builtin_amdgcn_mfma_f32_16x16x32_f16(
                        Hb[kc][m], bw[n][kc], acc[m][n], 0, 0, 0);

        // epilogue (single phase, rows 0..63 as 4 m-tiles of 16, but preT rows 0..31
        // per phase-pair m: store m-tile rows at (m&1)*16 + q*4 + r, section m>>1)
        // -> simpler: two half-phases like encoder to keep preT small
#pragma unroll
        for (int p = 0; p < 2; ++p) {
            if (p) __syncthreads();
#pragma unroll
            for (int m = 0; m < 2; ++m)
#pragma unroll
                for (int n = 0; n < 2; ++n)
#pragma unroll
                    for (int r = 0; r < 4; ++r)
                        preT[wave][n * 16 + n15][m * 16 + q * 4 + r] = acc[p * 2 + m][n][r];
            __syncthreads();
            if ((rT >> 5) == p) {   // threads owning rows [32p, 32p+32)
                const int rl = rT & 31;
                float pg[4][2];
#pragma unroll
                for (int g = 0; g < 4; ++g)
#pragma unroll
                    for (int e = 0; e < 2; ++e) {
                        const int col = (g >> 1) * 16 + (g & 1) * 8 + 2 * hcp + e;
                        pg[g][e] = preT[0][col][rl] + preT[1][col][rl]
                                 + preT[2][col][rl] + preT[3][col][rl] + fx[g][e];
                    }
                float hv[2];
#pragma unroll
                for (int e = 0; e < 2; ++e) {
                    const float ig = sigmoidf_(pg[0][e]);
                    const float fg = sigmoidf_(pg[1][e]);
                    const float gg = tanhf_(pg[2][e]);
                    const float og = sigmoidf_(pg[3][e]);
                    const float c  = fg * creg2[e] + ig * gg;
                    creg2[e] = c;
                    hv[e] = og * tanhf_(c);
                }
                *(float2*)(out + ((size_t)brow * T_ + (T_ - 1 - s)) * I_ + cc * 8 + 2 * hcp)
                    = float2{hv[0], hv[1]};
                const int j = cc * 8 + 2 * hcp;
                const int kch = j >> 5, j5 = j & 31;
                const int lt  = (rT & 15) | ((j5 >> 3) << 4);
                stg_h2_sc1(hnxt + ((size_t)(rg * 4 + (rT >> 4)) * 16 + kch) * 512
                                + lt * 8 + (j5 & 7), hv[0], hv[1]);
            }
        }

        wait_vm0();
        __syncthreads();
        if (tid == 0)
            __hip_atomic_store(&flags[blk], s + 1, __ATOMIC_RELAXED, __HIP_MEMORY_SCOPE_AGENT);
    }
}

// ---------------- launch ----------------
extern "C" void kernel_launch(void* const* d_in, const int* in_sizes, int n_in,
                              void* d_out_v, int out_size, void* d_ws, size_t ws_size,
                              hipStream_t stream) {
    (void)in_sizes; (void)n_in; (void)out_size; (void)ws_size;
    const float* x    = (const float*)d_in[0];
    const float* eWih = (const float*)d_in[1];
    const float* eWhh = (const float*)d_in[2];
    const float* ebih = (const float*)d_in[3];
    const float* ebhh = (const float*)d_in[4];
    const float* efcW = (const float*)d_in[5];
    const float* efcb = (const float*)d_in[6];
    const float* dfcW = (const float*)d_in[7];
    const float* dfcb = (const float*)d_in[8];
    const float* dWih = (const float*)d_in[9];
    const float* dWhh = (const float*)d_in[10];
    const float* dbih = (const float*)d_in[11];
    const float* dbhh = (const float*)d_in[12];
    float* d_out = (float*)d_out_v;

    char* ws = (char*)d_ws;
    size_t off = 0;
    auto carve = [&](size_t bytes) {
        char* p = ws + off;
        off += (bytes + 255) & ~(size_t)255;
        return p;
    };
    _Float16* xf     = (_Float16*)carve((size_t)B_ * T_ * I_ * 2);
    _Float16* hbufE  = (_Float16*)carve((size_t)2 * 262144 * 2);
    _Float16* hbufD  = (_Float16*)carve((size_t)2 * 131072 * 2);
    float*    c_e    = (float*)carve((size_t)B_ * H_ * 4);
    float*    fixedb = (float*)carve((size_t)B_ * 4 * I_ * 4);
    float*    dec1   = (float*)carve((size_t)B_ * H_ * 4);
    int*      flagsE = (int*)carve(256 * 4);
    int*      flagsD = (int*)carve(256 * 4);

    hipMemsetAsync(flagsE, 0, 256 * 4, stream);
    hipMemsetAsync(flagsD, 0, 256 * 4, stream);
    hipMemsetAsync(hbufE, 0, (size_t)262144 * 2, stream);   // h0 = 0 (buf 0)
    hipMemsetAsync(hbufD, 0, (size_t)131072 * 2, stream);   // hd0 = 0 (buf 0)

    shuffle_x_kernel<<<dim3(8192), 256, 0, stream>>>(x, xf);

    enc_persist<<<dim3(256), 256, 0, stream>>>(xf, eWih, eWhh, ebih, ebhh,
                                               hbufE, c_e, flagsE);

    float* embd = d_out + (size_t)B_ * T_ * I_;
    small_gemm_kernel<<<dim3(E_ / 32, B_ / 32), 256, 0, stream>>>(
        c_e, H_, efcW, H_, efcb, nullptr, embd, E_, H_, 1);
    small_gemm_kernel<<<dim3(H_ / 32, B_ / 32), 256, 0, stream>>>(
        embd, E_, dfcW, E_, dfcb, nullptr, dec1, H_, E_, 1);
    small_gemm_kernel<<<dim3(4 * I_ / 32, B_ / 32), 256, 0, stream>>>(
        dec1, H_, dWih, H_ + I_, dbih, dbhh, fixedb, 4 * I_, H_, 0);

    dec_persist<<<dim3(256), 256, 0, stream>>>(dWih, dWhh, fixedb,
                                               hbufD, d_out, flagsD);
}